// Round 7
// baseline (84.016 us; speedup 1.0000x reference)
//
#include <hip/hip_runtime.h>

#pragma clang fp contract(off)

#define TDIM 256
#define CDIM 64
#define SENT (-1e30f)
#define NPART 512           // absmax stage-1 blocks
#define WS_PART_OFF 16      // float offset of partials in d_ws

typedef __attribute__((ext_vector_type(8))) short bf16x8;
typedef __attribute__((ext_vector_type(4))) float f32x4;
typedef __attribute__((ext_vector_type(4))) int i32x4;

static constexpr float BOA = (float)(0.96963238 / 0.35815147);
static constexpr float COA = (float)(1.0 / 0.35815147);
static constexpr float AF  = 0.35815147f;
static constexpr float X0F = -0.6931f;

// Markstein exact division: r = RN(1/d) precomputed. Correctly-rounded IEEE
// quotient for normal operands (our ranges are safe) -> bit-identical to '/'.
__device__ __forceinline__ float exdiv(float x, float d, float r) {
  float q0 = x * r;
  float e = __builtin_fmaf(-d, q0, x);
  return __builtin_fmaf(e, r, q0);
}

__device__ __forceinline__ int qi8(float x, float s, float rs) {
  float t = rintf(exdiv(x, s, rs));
  t = fminf(fmaxf(t, -128.f), 127.f);
  return (int)t;
}

__device__ __forceinline__ int pack4q(float4 f, float s, float rs) {
  unsigned a = (unsigned)(qi8(f.x, s, rs)) & 255u;
  unsigned b = (unsigned)(qi8(f.y, s, rs)) & 255u;
  unsigned c = (unsigned)(qi8(f.z, s, rs)) & 255u;
  unsigned d = (unsigned)(qi8(f.w, s, rs)) & 255u;
  return (int)(a | (b << 8) | (c << 16) | (d << 24));
}

__device__ __forceinline__ int sx8(int w, int sh) {
  return (int)(signed char)((unsigned)w >> sh);
}

__device__ __forceinline__ unsigned short f2bf(float f) {
  // exact for our integer-valued inputs (|v| <= 256)
  return (unsigned short)(__float_as_uint(f) >> 16);
}

// ---- absmax stage 1: per-block partials, no atomics ----
__global__ __launch_bounds__(256) void absmax_partial_kernel(
    const float4* __restrict__ q, const float4* __restrict__ k,
    const float4* __restrict__ v, float* __restrict__ ws, int n4) {
  __shared__ float red[3][4];
  int tid = blockIdx.x * 256 + threadIdx.x;
  int stride = gridDim.x * 256;
  float m0 = 0.f, m1 = 0.f, m2 = 0.f;
  for (int i = tid; i < n4; i += stride) {
    float4 a = q[i];
    m0 = fmaxf(m0, fmaxf(fmaxf(fabsf(a.x), fabsf(a.y)), fmaxf(fabsf(a.z), fabsf(a.w))));
    float4 b = k[i];
    m1 = fmaxf(m1, fmaxf(fmaxf(fabsf(b.x), fabsf(b.y)), fmaxf(fabsf(b.z), fabsf(b.w))));
    float4 c = v[i];
    m2 = fmaxf(m2, fmaxf(fmaxf(fabsf(c.x), fabsf(c.y)), fmaxf(fabsf(c.z), fabsf(c.w))));
  }
#pragma unroll
  for (int off = 32; off > 0; off >>= 1) {
    m0 = fmaxf(m0, __shfl_xor(m0, off, 64));
    m1 = fmaxf(m1, __shfl_xor(m1, off, 64));
    m2 = fmaxf(m2, __shfl_xor(m2, off, 64));
  }
  int wave = threadIdx.x >> 6;
  if ((threadIdx.x & 63) == 0) {
    red[0][wave] = m0; red[1][wave] = m1; red[2][wave] = m2;
  }
  __syncthreads();
  if (threadIdx.x == 0) {
    ws[WS_PART_OFF + 0 * NPART + blockIdx.x] = fmaxf(fmaxf(red[0][0], red[0][1]), fmaxf(red[0][2], red[0][3]));
    ws[WS_PART_OFF + 1 * NPART + blockIdx.x] = fmaxf(fmaxf(red[1][0], red[1][1]), fmaxf(red[1][2], red[1][3]));
    ws[WS_PART_OFF + 2 * NPART + blockIdx.x] = fmaxf(fmaxf(red[2][0], red[2][1]), fmaxf(red[2][2], red[2][3]));
  }
}

// ---- absmax stage 2 ----
__global__ __launch_bounds__(256) void absmax_final_kernel(float* __restrict__ ws) {
  __shared__ float red[3][4];
  int tid = threadIdx.x;
  int wave = tid >> 6, lane = tid & 63;
#pragma unroll
  for (int j = 0; j < 3; ++j) {
    float v = fmaxf(ws[WS_PART_OFF + j * NPART + tid],
                    ws[WS_PART_OFF + j * NPART + tid + 256]);
#pragma unroll
    for (int off = 32; off > 0; off >>= 1) v = fmaxf(v, __shfl_xor(v, off, 64));
    if (lane == 0) red[j][wave] = v;
  }
  __syncthreads();
  if (tid == 0) {
#pragma unroll
    for (int j = 0; j < 3; ++j)
      ws[j] = fmaxf(fmaxf(red[j][0], red[j][1]), fmaxf(red[j][2], red[j][3]));
  }
}

// one block = one half-batch (128 rows); blockIdx.x = b*2 + half
__global__ __launch_bounds__(256, 3) void head_kernel(
    const float* __restrict__ qg, const float* __restrict__ kg,
    const float* __restrict__ vg, const float* __restrict__ ws,
    float* __restrict__ out, int out_size) {
  // K int8 in MFMA frag order: word idx = tile*256 + lane*4 + w (16 KB)
  __shared__ __align__(16) int kf[4096];
  // W row-major bf16 [slot][16 rows][264] (stride 528B); first 16.6 KB doubles
  // as V^T byte staging before the main loop.  Total LDS = 49 KB.
  __shared__ __align__(16) unsigned short wrow[4][16][264];

  const int tid = threadIdx.x;
  const int b = blockIdx.x >> 1;
  const int half = blockIdx.x & 1;      // 0: rows 0-127, 1: rows 128-255
  const int lane = tid & 63;
  const int wave = tid >> 6;
  const int hi = lane >> 4;
  const int s15 = lane & 15;

  // uniform scale pipeline constants (replicate reference f32 op order exactly)
  const float qsf = ws[0] / 127.f;
  const float ksf = ws[1] / 127.f;
  const float vsf = ws[2] / 127.f;
  const float sf = ksf * qsf;
  const float x0i = floorf(X0F / sf);
  const float bint = floorf(BOA / sf);
  const float cint = floorf(COA / (sf * sf));
  const float esf = ((AF * sf) * sf) * 0x1p-30f;
  const float emax = (cint * 0x1p30f) * esf;
  const float s16 = emax / 32767.f;
  const float clampv = 30.f * x0i;
  // hoisted IEEE reciprocals for Markstein
  const float rq = 1.f / qsf, rk = 1.f / ksf, rv = 1.f / vsf;
  const float rx0 = 1.f / x0i, rs16 = 1.f / s16;

  // ---- stage K and V^T (only the rows this half can see: 128 or 256) ----
  const float4* q4 = (const float4*)(qg + (size_t)b * (TDIM * CDIM));
  const float4* k4 = (const float4*)(kg + (size_t)b * (TDIM * CDIM));
  const float4* v4 = (const float4*)(vg + (size_t)b * (TDIM * CDIM));
  signed char* vst = (signed char*)wrow;   // V^T staging: [c][260B]
  const int nstage = 8 * (1 + half);       // 8 (BOT) or 16 (TOP) iterations
  for (int i = 0; i < nstage; ++i) {
    int vidx = i * 256 + tid;
    int row = vidx >> 4, cw = vidx & 15;
    int fidx = ((row >> 4) << 8) + ((row & 15) << 2) + ((cw >> 2) << 6) + (cw & 3);
    float4 f = k4[vidx];
    kf[fidx] = pack4q(f, ksf, rk);
    f = v4[vidx];
    int c0 = cw << 2;
    vst[(c0 + 0) * 260 + row] = (signed char)qi8(f.x, vsf, rv);
    vst[(c0 + 1) * 260 + row] = (signed char)qi8(f.y, vsf, rv);
    vst[(c0 + 2) * 260 + row] = (signed char)qi8(f.z, vsf, rv);
    vst[(c0 + 3) * 260 + row] = (signed char)qi8(f.w, vsf, rv);
  }
  __syncthreads();

  // ---- V -> per-lane bf16 B-frags (channel = wave*16 + s15) ----
  const int myc = (wave << 4) + s15;
  const int ksmax = 4 * (1 + half);        // valid k-chunks for this half
  bf16x8 vfrag[8];
#pragma unroll
  for (int ks = 0; ks < 8; ++ks) {
    bf16x8 bv = {0, 0, 0, 0, 0, 0, 0, 0};
    if (ks < ksmax) {
      const signed char* p = vst + myc * 260 + (ks << 5) + (hi << 3);
      int w0, w1;
      __builtin_memcpy(&w0, p, 4);
      __builtin_memcpy(&w1, p + 4, 4);
#pragma unroll
      for (int j = 0; j < 4; ++j) {
        bv[j]     = (short)f2bf((float)sx8(w0, j << 3));
        bv[4 + j] = (short)f2bf((float)sx8(w1, j << 3));
      }
    }
    vfrag[ks] = bv;
  }
  __syncthreads();

  // ---- zero W buffer (enables the stale-zero tail argument) ----
  {
    int* wz = (int*)wrow;
#pragma unroll
    for (int i = 0; i < 33; ++i) wz[i * 256 + tid] = 0;
  }
  __syncthreads();

  const i32x4 zero4 = {0, 0, 0, 0};

  // ---- main loop: 2 iterations, wave owns global row-tile R ----
#pragma unroll 1
  for (int it = 0; it < 2; ++it) {
    const int R = (half << 3) + (it << 2) + wave;

    // quantize this wave's Q A-frag directly from global (no LDS round-trip):
    // lane holds A[row = s15][k-bytes hi*16..+15] of tile R
    i32x4 aQ;
    {
      const float4* qrow4 = q4 + ((R << 4) + s15) * 16 + (hi << 2);
      aQ[0] = pack4q(qrow4[0], qsf, rq);
      aQ[1] = pack4q(qrow4[1], qsf, rq);
      aQ[2] = pack4q(qrow4[2], qsf, rq);
      aQ[3] = pack4q(qrow4[3], qsf, rq);
    }

    // QK^T via i8 MFMA; xi = x_int (exact), SENT where causally masked.
    // Sub-diagonal tiles (Cc < R) need no mask; only Cc == R does.
    float xi[16][4];
#pragma unroll
    for (int Cc = 0; Cc < 16; ++Cc) {
      if (Cc < R) {
        i32x4 bK = *(const i32x4*)(kf + (Cc << 8) + (lane << 2));
        i32x4 d = __builtin_amdgcn_mfma_i32_16x16x64_i8(aQ, bK, zero4, 0, 0, 0);
#pragma unroll
        for (int j = 0; j < 4; ++j) xi[Cc][j] = (float)d[j] * 0.125f;
      } else if (Cc == R) {
        i32x4 bK = *(const i32x4*)(kf + (Cc << 8) + (lane << 2));
        i32x4 d = __builtin_amdgcn_mfma_i32_16x16x64_i8(aQ, bK, zero4, 0, 0, 0);
#pragma unroll
        for (int j = 0; j < 4; ++j) {
          bool act = s15 <= ((hi << 2) + j);
          xi[Cc][j] = act ? (float)d[j] * 0.125f : SENT;
        }
      }
    }

    // integer softmax per row (j picks one of this lane-group's 4 rows)
#pragma unroll
    for (int j = 0; j < 4; ++j) {
      float mx = SENT;
#pragma unroll
      for (int Cc = 0; Cc < 16; ++Cc)
        if (Cc <= R) mx = fmaxf(mx, xi[Cc][j]);
      mx = fmaxf(mx, __shfl_xor(mx, 1, 64));
      mx = fmaxf(mx, __shfl_xor(mx, 2, 64));
      mx = fmaxf(mx, __shfl_xor(mx, 4, 64));
      mx = fmaxf(mx, __shfl_xor(mx, 8, 64));

      float lsum = 0.f;
#pragma unroll
      for (int Cc = 0; Cc < 16; ++Cc) {
        if (Cc <= R) {
          float x = xi[Cc][j] - mx;                 // masked: -1e30, caught by clamp
          x = fmaxf(x, clampv);
          float qv = floorf(exdiv(x, x0i, rx0));
          float rr = x - x0i * qv;                  // mul then sub (matches ref)
          float poly = (rr + bint) * rr + cint;     // contract off: no fused fma
          int iq = (int)qv;                         // in [0,30]
          float p2 = __int_as_float((157 - iq) << 23);  // exact 2^(30-q)
          float ef = fmaxf(floorf(poly * p2), 0.f);
          float xf = ef * esf;
          float v16 = fminf(rintf(exdiv(xf, s16, rs16)), 32767.f);
          float e = exdiv(v16 * s16, s16, rs16);
          xi[Cc][j] = e;                            // masked rows -> exactly 0
          lsum += e;
        }
      }
      lsum += __shfl_xor(lsum, 1, 64);
      lsum += __shfl_xor(lsum, 2, 64);
      lsum += __shfl_xor(lsum, 4, 64);
      lsum += __shfl_xor(lsum, 8, 64);

      float factor = floorf(4294967296.f / lsum);   // once per row, keep IEEE div
#pragma unroll
      for (int Cc = 0; Cc < 16; ++Cc) {
        if (Cc <= R) {
          float wqf = floorf((xi[Cc][j] * factor) * 0x1p-24f);
          wqf = fminf(fmaxf(wqf, 0.f), 256.f);
          wrow[wave][(hi << 2) + j][(Cc << 4) + s15] = f2bf(wqf);
        }
      }
    }
    __syncthreads();

    // PV: every wave consumes all 4 produced tiles (its 16 channels)
#pragma unroll
    for (int slot = 0; slot < 4; ++slot) {
      const int Rs = (half << 3) + (it << 2) + slot;
      const int ksn = (Rs + 2) >> 1;
      f32x4 acc = {0.f, 0.f, 0.f, 0.f};
      const unsigned short* wr = wrow[slot][s15];
#pragma unroll
      for (int ks = 0; ks < 8; ++ks) {
        if (ks < ksn) {
          bf16x8 a = *(const bf16x8*)(wr + (ks << 5) + (hi << 3));
          acc = __builtin_amdgcn_mfma_f32_16x16x32_bf16(a, vfrag[ks], acc, 0, 0, 0);
        }
      }
      const int rbase = (Rs << 4) + (hi << 2);
#pragma unroll
      for (int j = 0; j < 4; ++j)
        out[((b * TDIM) + rbase + j) * CDIM + myc] = (acc[j] * vsf) * 0x1p-16f;
    }
    __syncthreads();
  }

  if (blockIdx.x == 0 && tid == 0) out[out_size - 1] = 0.00390625f;  // wei_sf
}

extern "C" void kernel_launch(void* const* d_in, const int* in_sizes, int n_in,
                              void* d_out, int out_size, void* d_ws, size_t ws_size,
                              hipStream_t stream) {
  const float* q = (const float*)d_in[0];
  const float* k = (const float*)d_in[1];
  const float* v = (const float*)d_in[2];
  float* out = (float*)d_out;
  float* ws = (float*)d_ws;
  int n = in_sizes[0];               // B*T*C = 8388608
  int nb = n / (TDIM * CDIM);        // 512 batches

  absmax_partial_kernel<<<NPART, 256, 0, stream>>>((const float4*)q, (const float4*)k,
                                                   (const float4*)v, ws, n / 4);
  absmax_final_kernel<<<1, 256, 0, stream>>>(ws);
  head_kernel<<<nb * 2, 256, 0, stream>>>(q, k, v, (const float*)d_ws, out, out_size);
}

// Round 8
// 64.985 us; speedup vs baseline: 1.2928x; 1.2928x over previous
//
#include <hip/hip_runtime.h>

#pragma clang fp contract(off)

#define TDIM 256
#define CDIM 64
#define SENT (-1e30f)
#define NPART 512           // absmax stage-1 blocks
#define WS_PART_OFF 16      // float offset of partials in d_ws

typedef __attribute__((ext_vector_type(8))) short bf16x8;
typedef __attribute__((ext_vector_type(4))) float f32x4;
typedef __attribute__((ext_vector_type(4))) int i32x4;

static constexpr float BOA = (float)(0.96963238 / 0.35815147);
static constexpr float COA = (float)(1.0 / 0.35815147);
static constexpr float AF  = 0.35815147f;
static constexpr float X0F = -0.6931f;

// Markstein exact division: r = RN(1/d) precomputed. Correctly-rounded IEEE
// quotient for normal operands (our ranges are safe) -> bit-identical to '/'.
__device__ __forceinline__ float exdiv(float x, float d, float r) {
  float q0 = x * r;
  float e = __builtin_fmaf(-d, q0, x);
  return __builtin_fmaf(e, r, q0);
}

__device__ __forceinline__ int qi8(float x, float s, float rs) {
  float t = rintf(exdiv(x, s, rs));
  t = fminf(fmaxf(t, -128.f), 127.f);
  return (int)t;
}

__device__ __forceinline__ int pack4q(float4 f, float s, float rs) {
  unsigned a = (unsigned)(qi8(f.x, s, rs)) & 255u;
  unsigned b = (unsigned)(qi8(f.y, s, rs)) & 255u;
  unsigned c = (unsigned)(qi8(f.z, s, rs)) & 255u;
  unsigned d = (unsigned)(qi8(f.w, s, rs)) & 255u;
  return (int)(a | (b << 8) | (c << 16) | (d << 24));
}

__device__ __forceinline__ int sx8(int w, int sh) {
  return (int)(signed char)((unsigned)w >> sh);
}

__device__ __forceinline__ unsigned f2bfu(float f) {
  // exact for our integer-valued inputs (|v| <= 256)
  return __float_as_uint(f) >> 16;
}

// ---- absmax stage 1: per-block partials, no atomics ----
__global__ __launch_bounds__(256) void absmax_partial_kernel(
    const float4* __restrict__ q, const float4* __restrict__ k,
    const float4* __restrict__ v, float* __restrict__ ws, int n4) {
  __shared__ float red[3][4];
  int tid = blockIdx.x * 256 + threadIdx.x;
  int stride = gridDim.x * 256;
  float m0 = 0.f, m1 = 0.f, m2 = 0.f;
  for (int i = tid; i < n4; i += stride) {
    float4 a = q[i];
    m0 = fmaxf(m0, fmaxf(fmaxf(fabsf(a.x), fabsf(a.y)), fmaxf(fabsf(a.z), fabsf(a.w))));
    float4 b = k[i];
    m1 = fmaxf(m1, fmaxf(fmaxf(fabsf(b.x), fabsf(b.y)), fmaxf(fabsf(b.z), fabsf(b.w))));
    float4 c = v[i];
    m2 = fmaxf(m2, fmaxf(fmaxf(fabsf(c.x), fabsf(c.y)), fmaxf(fabsf(c.z), fabsf(c.w))));
  }
#pragma unroll
  for (int off = 32; off > 0; off >>= 1) {
    m0 = fmaxf(m0, __shfl_xor(m0, off, 64));
    m1 = fmaxf(m1, __shfl_xor(m1, off, 64));
    m2 = fmaxf(m2, __shfl_xor(m2, off, 64));
  }
  int wave = threadIdx.x >> 6;
  if ((threadIdx.x & 63) == 0) {
    red[0][wave] = m0; red[1][wave] = m1; red[2][wave] = m2;
  }
  __syncthreads();
  if (threadIdx.x == 0) {
    ws[WS_PART_OFF + 0 * NPART + blockIdx.x] = fmaxf(fmaxf(red[0][0], red[0][1]), fmaxf(red[0][2], red[0][3]));
    ws[WS_PART_OFF + 1 * NPART + blockIdx.x] = fmaxf(fmaxf(red[1][0], red[1][1]), fmaxf(red[1][2], red[1][3]));
    ws[WS_PART_OFF + 2 * NPART + blockIdx.x] = fmaxf(fmaxf(red[2][0], red[2][1]), fmaxf(red[2][2], red[2][3]));
  }
}

// ---- absmax stage 2 ----
__global__ __launch_bounds__(256) void absmax_final_kernel(float* __restrict__ ws) {
  __shared__ float red[3][4];
  int tid = threadIdx.x;
  int wave = tid >> 6, lane = tid & 63;
#pragma unroll
  for (int j = 0; j < 3; ++j) {
    float v = fmaxf(ws[WS_PART_OFF + j * NPART + tid],
                    ws[WS_PART_OFF + j * NPART + tid + 256]);
#pragma unroll
    for (int off = 32; off > 0; off >>= 1) v = fmaxf(v, __shfl_xor(v, off, 64));
    if (lane == 0) red[j][wave] = v;
  }
  __syncthreads();
  if (tid == 0) {
#pragma unroll
    for (int j = 0; j < 3; ++j)
      ws[j] = fmaxf(fmaxf(red[j][0], red[j][1]), fmaxf(red[j][2], red[j][3]));
  }
}

__global__ __launch_bounds__(256, 2) void head_kernel(
    const float* __restrict__ qg, const float* __restrict__ kg,
    const float* __restrict__ vg, const float* __restrict__ ws,
    float* __restrict__ out, int out_size) {
  // K int8 in MFMA frag order: word idx = tile*256 + lane*4 + w (16 KB)
  __shared__ __align__(16) int kf[4096];
  // W row-major bf16 [slot][16 q-rows][264] (stride 528B); first 16.6 KB
  // doubles as V^T byte staging before the main loop.  Total LDS = 49 KB.
  __shared__ __align__(16) unsigned short wrow[4][16][264];

  const int tid = threadIdx.x;
  const int b = blockIdx.x;
  const int lane = tid & 63;
  const int wave = tid >> 6;
  const int hi = lane >> 4;
  const int s15 = lane & 15;

  // uniform scale pipeline constants (replicate reference f32 op order exactly)
  const float qsf = ws[0] / 127.f;
  const float ksf = ws[1] / 127.f;
  const float vsf = ws[2] / 127.f;
  const float sf = ksf * qsf;
  const float x0i = floorf(X0F / sf);
  const float bint = floorf(BOA / sf);
  const float cint = floorf(COA / (sf * sf));
  const float esf = ((AF * sf) * sf) * 0x1p-30f;
  const float emax = (cint * 0x1p30f) * esf;
  const float s16 = emax / 32767.f;
  const float clampv = 30.f * x0i;
  // hoisted IEEE reciprocals for Markstein
  const float rq = 1.f / qsf, rk = 1.f / ksf, rv = 1.f / vsf;
  const float rx0 = 1.f / x0i, rs16 = 1.f / s16;

  // ---- stage K (frag order) and V^T (bytes) ----
  const float4* q4 = (const float4*)(qg + (size_t)b * (TDIM * CDIM));
  const float4* k4 = (const float4*)(kg + (size_t)b * (TDIM * CDIM));
  const float4* v4 = (const float4*)(vg + (size_t)b * (TDIM * CDIM));
  signed char* vst = (signed char*)wrow;   // V^T staging: [c][260B]
#pragma unroll
  for (int i = 0; i < 16; ++i) {
    int vidx = i * 256 + tid;
    int row = vidx >> 4, cw = vidx & 15;
    int fidx = ((row >> 4) << 8) + ((row & 15) << 2) + ((cw >> 2) << 6) + (cw & 3);
    float4 f = k4[vidx];
    kf[fidx] = pack4q(f, ksf, rk);
    f = v4[vidx];
    int c0 = cw << 2;
    vst[(c0 + 0) * 260 + row] = (signed char)qi8(f.x, vsf, rv);
    vst[(c0 + 1) * 260 + row] = (signed char)qi8(f.y, vsf, rv);
    vst[(c0 + 2) * 260 + row] = (signed char)qi8(f.z, vsf, rv);
    vst[(c0 + 3) * 260 + row] = (signed char)qi8(f.w, vsf, rv);
  }
  __syncthreads();

  // ---- V -> per-lane bf16 B-frags (channel = wave*16 + s15) ----
  const int myc = (wave << 4) + s15;
  bf16x8 vfrag[8];
#pragma unroll
  for (int ks = 0; ks < 8; ++ks) {
    const signed char* p = vst + myc * 260 + (ks << 5) + (hi << 3);
    int w0, w1;
    __builtin_memcpy(&w0, p, 4);
    __builtin_memcpy(&w1, p + 4, 4);
    bf16x8 bv;
#pragma unroll
    for (int j = 0; j < 4; ++j) {
      bv[j]     = (short)f2bfu((float)sx8(w0, j << 3));
      bv[4 + j] = (short)f2bfu((float)sx8(w1, j << 3));
    }
    vfrag[ks] = bv;
  }
  __syncthreads();

  // ---- zero W buffer (stale-zero tail + never-written tiles) ----
  {
    int* wz = (int*)wrow;
#pragma unroll
    for (int i = 0; i < 33; ++i) wz[i * 256 + tid] = 0;
  }
  __syncthreads();

  const i32x4 zero4 = {0, 0, 0, 0};

  // Q prefetch for iteration 0: lane holds Q row s15 of tile R, bytes hi*16..+15
  float4 qld0, qld1, qld2, qld3;
  {
    const float4* p = q4 + ((wave << 4) + s15) * 16 + (hi << 2);
    qld0 = p[0]; qld1 = p[1]; qld2 = p[2]; qld3 = p[3];
  }

  // ---- main loop: 4 iterations, wave owns row-tile R = it*4 + wave ----
#pragma unroll 1
  for (int it = 0; it < 4; ++it) {
    const int R = (it << 2) + wave;

    i32x4 aQ;
    aQ[0] = pack4q(qld0, qsf, rq);
    aQ[1] = pack4q(qld1, qsf, rq);
    aQ[2] = pack4q(qld2, qsf, rq);
    aQ[3] = pack4q(qld3, qsf, rq);

    // swapped QK^T: D = K_tile * Q_tile -> lane holds ONE q-row (s15),
    // k = Cc*16 + hi*4 + j.  xi = x_int (exact), SENT where masked.
    float xi[16][4];
#pragma unroll
    for (int Cc = 0; Cc < 16; ++Cc) {
      if (Cc < R) {
        i32x4 bK = *(const i32x4*)(kf + (Cc << 8) + (lane << 2));
        i32x4 d = __builtin_amdgcn_mfma_i32_16x16x64_i8(bK, aQ, zero4, 0, 0, 0);
#pragma unroll
        for (int j = 0; j < 4; ++j) xi[Cc][j] = (float)d[j] * 0.125f;
      } else if (Cc == R) {
        i32x4 bK = *(const i32x4*)(kf + (Cc << 8) + (lane << 2));
        i32x4 d = __builtin_amdgcn_mfma_i32_16x16x64_i8(bK, aQ, zero4, 0, 0, 0);
#pragma unroll
        for (int j = 0; j < 4; ++j) {
          bool act = ((hi << 2) + j) <= s15;        // k_local <= q_local
          xi[Cc][j] = act ? (float)d[j] * 0.125f : SENT;
        }
      }
    }

    // prefetch next iteration's Q while softmax/PV run
    if (it < 3) {
      const float4* p = q4 + (((R + 4) << 4) + s15) * 16 + (hi << 2);
      qld0 = p[0]; qld1 = p[1]; qld2 = p[2]; qld3 = p[3];
    }

    // ---- row max: in-register tree + 2 shfls ----
    float mloc[16];
#pragma unroll
    for (int Cc = 0; Cc < 16; ++Cc)
      mloc[Cc] = (Cc <= R)
                     ? fmaxf(fmaxf(xi[Cc][0], xi[Cc][1]), fmaxf(xi[Cc][2], xi[Cc][3]))
                     : SENT;
#pragma unroll
    for (int st = 8; st > 0; st >>= 1)
#pragma unroll
      for (int c = 0; c < st; ++c) mloc[c] = fmaxf(mloc[c], mloc[c + st]);
    float mx = fmaxf(mloc[0], __shfl_xor(mloc[0], 16, 64));
    mx = fmaxf(mx, __shfl_xor(mx, 32, 64));

    // ---- integer-softmax pipeline (exact f32 replica), per-lane row ----
    float sloc[16];
#pragma unroll
    for (int Cc = 0; Cc < 16; ++Cc) {
      float s = 0.f;
      if (Cc <= R) {
#pragma unroll
        for (int j = 0; j < 4; ++j) {
          float x = xi[Cc][j] - mx;                 // masked: -1e30, clamp catches
          x = fmaxf(x, clampv);
          float qv = floorf(exdiv(x, x0i, rx0));
          float rr = x - x0i * qv;                  // mul then sub (matches ref)
          float poly = (rr + bint) * rr + cint;     // contract off: no fused fma
          int iq = (int)qv;                         // in [0,30]
          float p2 = __int_as_float((157 - iq) << 23);  // exact 2^(30-q)
          float ef = fmaxf(floorf(poly * p2), 0.f);
          float xf = ef * esf;
          float v16 = fminf(rintf(exdiv(xf, s16, rs16)), 32767.f);
          float e = exdiv(v16 * s16, s16, rs16);
          xi[Cc][j] = e;                            // masked -> exactly 0
          s += e;
        }
      }
      sloc[Cc] = s;
    }
#pragma unroll
    for (int st = 8; st > 0; st >>= 1)
#pragma unroll
      for (int c = 0; c < st; ++c) sloc[c] += sloc[c + st];
    float lsum = sloc[0] + __shfl_xor(sloc[0], 16, 64);
    lsum += __shfl_xor(lsum, 32, 64);

    float factor = floorf(4294967296.f / lsum);     // one per lane (its row)

    // ---- W store: packed b64 per tile, row = s15, col = Cc*16+hi*4+j ----
#pragma unroll
    for (int Cc = 0; Cc < 16; ++Cc) {
      if (Cc <= R) {
        float w0 = fminf(fmaxf(floorf((xi[Cc][0] * factor) * 0x1p-24f), 0.f), 256.f);
        float w1 = fminf(fmaxf(floorf((xi[Cc][1] * factor) * 0x1p-24f), 0.f), 256.f);
        float w2 = fminf(fmaxf(floorf((xi[Cc][2] * factor) * 0x1p-24f), 0.f), 256.f);
        float w3 = fminf(fmaxf(floorf((xi[Cc][3] * factor) * 0x1p-24f), 0.f), 256.f);
        uint2 pk;
        pk.x = f2bfu(w0) | (f2bfu(w1) << 16);
        pk.y = f2bfu(w2) | (f2bfu(w3) << 16);
        *(uint2*)&wrow[wave][s15][(Cc << 4) + (hi << 2)] = pk;
      }
    }
    __syncthreads();

    // ---- PV: every wave consumes all 4 produced tiles (its 16 channels) ----
#pragma unroll
    for (int slot = 0; slot < 4; ++slot) {
      const int Rs = (it << 2) + slot;
      const int ksn = (Rs + 2) >> 1;
      f32x4 acc = {0.f, 0.f, 0.f, 0.f};
      const unsigned short* wr = wrow[slot][s15];
#pragma unroll
      for (int ks = 0; ks < 8; ++ks) {
        if (ks < ksn) {
          bf16x8 a = *(const bf16x8*)(wr + (ks << 5) + (hi << 3));
          acc = __builtin_amdgcn_mfma_f32_16x16x32_bf16(a, vfrag[ks], acc, 0, 0, 0);
        }
      }
      const int rbase = (Rs << 4) + (hi << 2);
#pragma unroll
      for (int j = 0; j < 4; ++j)
        out[((b * TDIM) + rbase + j) * CDIM + myc] = (acc[j] * vsf) * 0x1p-16f;
    }
    __syncthreads();
  }

  if (b == 0 && tid == 0) out[out_size - 1] = 0.00390625f;  // wei_sf
}

extern "C" void kernel_launch(void* const* d_in, const int* in_sizes, int n_in,
                              void* d_out, int out_size, void* d_ws, size_t ws_size,
                              hipStream_t stream) {
  const float* q = (const float*)d_in[0];
  const float* k = (const float*)d_in[1];
  const float* v = (const float*)d_in[2];
  float* out = (float*)d_out;
  float* ws = (float*)d_ws;
  int n = in_sizes[0];               // B*T*C = 8388608
  int nb = n / (TDIM * CDIM);        // 512 batches

  absmax_partial_kernel<<<NPART, 256, 0, stream>>>((const float4*)q, (const float4*)k,
                                                   (const float4*)v, ws, n / 4);
  absmax_final_kernel<<<1, 256, 0, stream>>>(ws);
  head_kernel<<<nb, 256, 0, stream>>>(q, k, v, (const float*)d_ws, out, out_size);
}

// Round 9
// 63.969 us; speedup vs baseline: 1.3134x; 1.0159x over previous
//
#include <hip/hip_runtime.h>

#pragma clang fp contract(off)

#define TDIM 256
#define CDIM 64
#define SENT (-1e30f)
#define NPART 512           // absmax stage-1 blocks
#define WS_PART_OFF 16      // float offset of partials in d_ws

typedef __attribute__((ext_vector_type(8))) short bf16x8;
typedef __attribute__((ext_vector_type(4))) float f32x4;
typedef __attribute__((ext_vector_type(4))) int i32x4;

static constexpr float BOA = (float)(0.96963238 / 0.35815147);
static constexpr float COA = (float)(1.0 / 0.35815147);
static constexpr float AF  = 0.35815147f;
static constexpr float X0F = -0.6931f;

// Markstein exact division: r = RN(1/d) precomputed -> correctly-rounded IEEE
// quotient for our (normal-range) operands, bit-identical to '/'.
__device__ __forceinline__ float exdiv(float x, float d, float r) {
  float q0 = x * r;
  float e = __builtin_fmaf(-d, q0, x);
  return __builtin_fmaf(e, r, q0);
}

__device__ __forceinline__ float q8f(float x, float s, float rs) {
  float t = rintf(exdiv(x, s, rs));
  return fminf(fmaxf(t, -128.f), 127.f);   // quantized value as exact float
}

__device__ __forceinline__ int pack4q(float4 f, float s, float rs) {
  unsigned a = (unsigned)(int)q8f(f.x, s, rs) & 255u;
  unsigned b = (unsigned)(int)q8f(f.y, s, rs) & 255u;
  unsigned c = (unsigned)(int)q8f(f.z, s, rs) & 255u;
  unsigned d = (unsigned)(int)q8f(f.w, s, rs) & 255u;
  return (int)(a | (b << 8) | (c << 16) | (d << 24));
}

__device__ __forceinline__ unsigned f2bfu(float f) {
  // exact truncation for integer-valued |f| <= 256 (<= 9 significant bits)
  return __float_as_uint(f) >> 16;
}

__device__ __forceinline__ bf16x8 mk_bf16x8(unsigned a0, unsigned a1,
                                            unsigned a2, unsigned a3) {
  union { unsigned u[4]; bf16x8 h; } t;
  t.u[0] = a0; t.u[1] = a1; t.u[2] = a2; t.u[3] = a3;
  return t.h;
}

// ---- absmax stage 1: per-block partials, no atomics ----
__global__ __launch_bounds__(256) void absmax_partial_kernel(
    const float4* __restrict__ q, const float4* __restrict__ k,
    const float4* __restrict__ v, float* __restrict__ ws, int n4) {
  __shared__ float red[3][4];
  int tid = blockIdx.x * 256 + threadIdx.x;
  int stride = gridDim.x * 256;
  float m0 = 0.f, m1 = 0.f, m2 = 0.f;
  for (int i = tid; i < n4; i += stride) {
    float4 a = q[i];
    m0 = fmaxf(m0, fmaxf(fmaxf(fabsf(a.x), fabsf(a.y)), fmaxf(fabsf(a.z), fabsf(a.w))));
    float4 b = k[i];
    m1 = fmaxf(m1, fmaxf(fmaxf(fabsf(b.x), fabsf(b.y)), fmaxf(fabsf(b.z), fabsf(b.w))));
    float4 c = v[i];
    m2 = fmaxf(m2, fmaxf(fmaxf(fabsf(c.x), fabsf(c.y)), fmaxf(fabsf(c.z), fabsf(c.w))));
  }
#pragma unroll
  for (int off = 32; off > 0; off >>= 1) {
    m0 = fmaxf(m0, __shfl_xor(m0, off, 64));
    m1 = fmaxf(m1, __shfl_xor(m1, off, 64));
    m2 = fmaxf(m2, __shfl_xor(m2, off, 64));
  }
  int wave = threadIdx.x >> 6;
  if ((threadIdx.x & 63) == 0) {
    red[0][wave] = m0; red[1][wave] = m1; red[2][wave] = m2;
  }
  __syncthreads();
  if (threadIdx.x == 0) {
    ws[WS_PART_OFF + 0 * NPART + blockIdx.x] = fmaxf(fmaxf(red[0][0], red[0][1]), fmaxf(red[0][2], red[0][3]));
    ws[WS_PART_OFF + 1 * NPART + blockIdx.x] = fmaxf(fmaxf(red[1][0], red[1][1]), fmaxf(red[1][2], red[1][3]));
    ws[WS_PART_OFF + 2 * NPART + blockIdx.x] = fmaxf(fmaxf(red[2][0], red[2][1]), fmaxf(red[2][2], red[2][3]));
  }
}

// ---- absmax stage 2 ----
__global__ __launch_bounds__(256) void absmax_final_kernel(float* __restrict__ ws) {
  __shared__ float red[3][4];
  int tid = threadIdx.x;
  int wave = tid >> 6, lane = tid & 63;
#pragma unroll
  for (int j = 0; j < 3; ++j) {
    float v = fmaxf(ws[WS_PART_OFF + j * NPART + tid],
                    ws[WS_PART_OFF + j * NPART + tid + 256]);
#pragma unroll
    for (int off = 32; off > 0; off >>= 1) v = fmaxf(v, __shfl_xor(v, off, 64));
    if (lane == 0) red[j][wave] = v;
  }
  __syncthreads();
  if (tid == 0) {
#pragma unroll
    for (int j = 0; j < 3; ++j)
      ws[j] = fmaxf(fmaxf(red[j][0], red[j][1]), fmaxf(red[j][2], red[j][3]));
  }
}

__global__ __launch_bounds__(256, 2) void head_kernel(
    const float* __restrict__ qg, const float* __restrict__ kg,
    const float* __restrict__ vg, const float* __restrict__ ws,
    float* __restrict__ out, int out_size) {
  // K int8 in MFMA frag order: word idx = tile*256 + lane*4 + w (16 KB)
  __shared__ __align__(16) int kf[4096];
  // V^T as bf16: vbf[ch][k], stride 264 shorts (528 B). Read-only after the
  // single prologue barrier -> the main loop has NO barriers at all.
  __shared__ __align__(16) unsigned short vbf[CDIM][264];

  const int tid = threadIdx.x;
  const int b = blockIdx.x;
  const int lane = tid & 63;
  const int wave = tid >> 6;
  const int hi = lane >> 4;
  const int s15 = lane & 15;

  // uniform scale pipeline constants (replicate reference f32 op order exactly)
  const float qsf = ws[0] / 127.f;
  const float ksf = ws[1] / 127.f;
  const float vsf = ws[2] / 127.f;
  const float sf = ksf * qsf;
  const float x0i = floorf(X0F / sf);
  const float bint = floorf(BOA / sf);
  const float cint = floorf(COA / (sf * sf));
  const float esf = ((AF * sf) * sf) * 0x1p-30f;
  const float emax = (cint * 0x1p30f) * esf;
  const float s16 = emax / 32767.f;
  const float clampv = 30.f * x0i;
  const float rq = 1.f / qsf, rk = 1.f / ksf, rv = 1.f / vsf;
  const float rx0 = 1.f / x0i, rs16 = 1.f / s16;

  // ---- stage K (i8 frag order) and V^T (bf16) ----
  const float4* q4 = (const float4*)(qg + (size_t)b * (TDIM * CDIM));
  const float4* k4 = (const float4*)(kg + (size_t)b * (TDIM * CDIM));
  const float4* v4 = (const float4*)(vg + (size_t)b * (TDIM * CDIM));
#pragma unroll
  for (int i = 0; i < 16; ++i) {
    int vidx = i * 256 + tid;
    int row = vidx >> 4, cw = vidx & 15;
    int fidx = ((row >> 4) << 8) + ((row & 15) << 2) + ((cw >> 2) << 6) + (cw & 3);
    float4 f = k4[vidx];
    kf[fidx] = pack4q(f, ksf, rk);
    f = v4[vidx];
    int c0 = cw << 2;
    vbf[c0 + 0][row] = (unsigned short)f2bfu(q8f(f.x, vsf, rv));
    vbf[c0 + 1][row] = (unsigned short)f2bfu(q8f(f.y, vsf, rv));
    vbf[c0 + 2][row] = (unsigned short)f2bfu(q8f(f.z, vsf, rv));
    vbf[c0 + 3][row] = (unsigned short)f2bfu(q8f(f.w, vsf, rv));
  }
  __syncthreads();   // the only barrier: kf/vbf are read-only afterwards

  const i32x4 zero4 = {0, 0, 0, 0};

  // Q prefetch for first tile (R = wave)
  float4 qldA, qldB, qldC, qldD;
  {
    const float4* p = q4 + ((wave << 4) + s15) * 16 + (hi << 2);
    qldA = p[0]; qldB = p[1]; qldC = p[2]; qldD = p[3];
  }

  // ---- main loop: 4 independent tiles per wave, balanced {w,7-w,8+w,15-w} ----
#pragma unroll 1
  for (int itt = 0; itt < 4; ++itt) {
    const int R = ((itt & 2) << 2) | ((itt & 1) ? (7 - wave) : wave);

    i32x4 aQ;
    aQ[0] = pack4q(qldA, qsf, rq);
    aQ[1] = pack4q(qldB, qsf, rq);
    aQ[2] = pack4q(qldC, qsf, rq);
    aQ[3] = pack4q(qldD, qsf, rq);

    // prefetch next tile's Q while QK/softmax run
    if (itt < 3) {
      const int Rn = (((itt + 1) & 2) << 2) | (((itt + 1) & 1) ? (7 - wave) : wave);
      const float4* p = q4 + ((Rn << 4) + s15) * 16 + (hi << 2);
      qldA = p[0]; qldB = p[1]; qldC = p[2]; qldD = p[3];
    }

    // swapped QK^T: lane holds ONE q-row (s15); k = Cc*16 + hi*4 + j
    float xi[16][4];
#pragma unroll
    for (int Cc = 0; Cc < 16; ++Cc) {
      if (Cc < R) {
        i32x4 bK = *(const i32x4*)(kf + (Cc << 8) + (lane << 2));
        i32x4 d = __builtin_amdgcn_mfma_i32_16x16x64_i8(bK, aQ, zero4, 0, 0, 0);
#pragma unroll
        for (int j = 0; j < 4; ++j) xi[Cc][j] = (float)d[j] * 0.125f;
      } else if (Cc == R) {
        i32x4 bK = *(const i32x4*)(kf + (Cc << 8) + (lane << 2));
        i32x4 d = __builtin_amdgcn_mfma_i32_16x16x64_i8(bK, aQ, zero4, 0, 0, 0);
#pragma unroll
        for (int j = 0; j < 4; ++j) {
          bool act = ((hi << 2) + j) <= s15;        // k_local <= q_local
          xi[Cc][j] = act ? (float)d[j] * 0.125f : SENT;
        }
      }
    }

    // ---- row max: in-register tree + 2 shfls (identical to r8) ----
    float mloc[16];
#pragma unroll
    for (int Cc = 0; Cc < 16; ++Cc)
      mloc[Cc] = (Cc <= R)
                     ? fmaxf(fmaxf(xi[Cc][0], xi[Cc][1]), fmaxf(xi[Cc][2], xi[Cc][3]))
                     : SENT;
#pragma unroll
    for (int st = 8; st > 0; st >>= 1)
#pragma unroll
      for (int c = 0; c < st; ++c) mloc[c] = fmaxf(mloc[c], mloc[c + st]);
    float mx = fmaxf(mloc[0], __shfl_xor(mloc[0], 16, 64));
    mx = fmaxf(mx, __shfl_xor(mx, 32, 64));

    // ---- integer-softmax pipeline (exact f32 replica, identical order) ----
    float sloc[16];
#pragma unroll
    for (int Cc = 0; Cc < 16; ++Cc) {
      float s = 0.f;
      if (Cc <= R) {
#pragma unroll
        for (int j = 0; j < 4; ++j) {
          float x = xi[Cc][j] - mx;                 // masked: -1e30, clamp catches
          x = fmaxf(x, clampv);
          float qv = floorf(exdiv(x, x0i, rx0));
          float rr = x - x0i * qv;                  // mul then sub (matches ref)
          float poly = (rr + bint) * rr + cint;     // contract off: no fused fma
          int iq = (int)qv;                         // in [0,30]
          float p2 = __int_as_float((157 - iq) << 23);  // exact 2^(30-q)
          float ef = fmaxf(floorf(poly * p2), 0.f);
          float xf = ef * esf;
          float v16 = fminf(rintf(exdiv(xf, s16, rs16)), 32767.f);
          float e = exdiv(v16 * s16, s16, rs16);
          xi[Cc][j] = e;                            // masked -> exactly 0
          s += e;
        }
      }
      sloc[Cc] = s;
    }
#pragma unroll
    for (int st = 8; st > 0; st >>= 1)
#pragma unroll
      for (int c = 0; c < st; ++c) sloc[c] += sloc[c + st];
    float lsum = sloc[0] + __shfl_xor(sloc[0], 16, 64);
    lsum += __shfl_xor(lsum, 32, 64);

    float factor = floorf(4294967296.f / lsum);
    // exact: RN(e*factor)*2^-24 == RN(e*(factor*2^-24)); wq in [0,256] provably
    const float factor24 = factor * 0x1p-24f;

    // ---- W pack: wp[Cc] = 2 words of 4 bf16 (k = 16Cc + 4hi + j) ----
    unsigned wp[16][2];
#pragma unroll
    for (int Cc = 0; Cc < 16; ++Cc) {
      if (Cc <= R) {
        float w0 = floorf(xi[Cc][0] * factor24);
        float w1 = floorf(xi[Cc][1] * factor24);
        float w2 = floorf(xi[Cc][2] * factor24);
        float w3 = floorf(xi[Cc][3] * factor24);
        wp[Cc][0] = f2bfu(w0) | (f2bfu(w1) << 16);
        wp[Cc][1] = f2bfu(w2) | (f2bfu(w3) << 16);
      }
    }

    // ---- PV in-register: A = wp (k-label = 16Cc+4hi+j), B read with the
    //      SAME k-label bijection -> no transpose, no LDS W, no barrier.
    const int ksn = (R + 2) >> 1;
    f32x4 acc[4] = {{0.f, 0.f, 0.f, 0.f}, {0.f, 0.f, 0.f, 0.f},
                    {0.f, 0.f, 0.f, 0.f}, {0.f, 0.f, 0.f, 0.f}};
#pragma unroll
    for (int ks = 0; ks < 8; ++ks) {
      if (ks < ksn) {
        unsigned a2 = 0, a3 = 0;
        if (2 * ks + 1 <= R) { a2 = wp[2 * ks + 1][0]; a3 = wp[2 * ks + 1][1]; }
        bf16x8 af = mk_bf16x8(wp[2 * ks][0], wp[2 * ks][1], a2, a3);
#pragma unroll
        for (int g = 0; g < 4; ++g) {
          const unsigned short* pb = &vbf[(g << 4) + s15][(ks << 5) + (hi << 2)];
          unsigned b0, b1, b2, b3;
          __builtin_memcpy(&b0, pb, 4);
          __builtin_memcpy(&b1, pb + 2, 4);
          __builtin_memcpy(&b2, pb + 16, 4);
          __builtin_memcpy(&b3, pb + 18, 4);
          bf16x8 bf_ = mk_bf16x8(b0, b1, b2, b3);
          acc[g] = __builtin_amdgcn_mfma_f32_16x16x32_bf16(af, bf_, acc[g], 0, 0, 0);
        }
      }
    }

    // ---- out: rows R*16 + hi*4 + j, channels g*16 + s15 ----
    const int rb = (R << 4) + (hi << 2);
#pragma unroll
    for (int g = 0; g < 4; ++g)
#pragma unroll
      for (int j = 0; j < 4; ++j)
        out[((b * TDIM) + rb + j) * CDIM + (g << 4) + s15] = (acc[g][j] * vsf) * 0x1p-16f;
  }

  if (b == 0 && tid == 0) out[out_size - 1] = 0.00390625f;  // wei_sf
}

extern "C" void kernel_launch(void* const* d_in, const int* in_sizes, int n_in,
                              void* d_out, int out_size, void* d_ws, size_t ws_size,
                              hipStream_t stream) {
  const float* q = (const float*)d_in[0];
  const float* k = (const float*)d_in[1];
  const float* v = (const float*)d_in[2];
  float* out = (float*)d_out;
  float* ws = (float*)d_ws;
  int n = in_sizes[0];               // B*T*C = 8388608
  int nb = n / (TDIM * CDIM);        // 512 batches

  absmax_partial_kernel<<<NPART, 256, 0, stream>>>((const float4*)q, (const float4*)k,
                                                   (const float4*)v, ws, n / 4);
  absmax_final_kernel<<<1, 256, 0, stream>>>(ws);
  head_kernel<<<nb, 256, 0, stream>>>(q, k, v, (const float*)d_ws, out, out_size);
}